// Round 7
// baseline (713.941 us; speedup 1.0000x reference)
//
#include <hip/hip_runtime.h>

// SimpleRecGNN: 6-layer GCN, N=200000 nodes, E=2000000 edges, dims 16->32(x5)->16.
// CSR of 8B records {src,w} built per launch via 3-pass bucketed build:
//  1) bucketize: tile-local LDS histogram over 8 dest-ranges -> block reserves
//     contiguous per-bucket runs -> coalesced SoA record writes (no line ampl.)
//  2) bcount: per-bucket count into XCD-local cnt slice (part = blockIdx&7)
//  3) bscatter: per-bucket scatter into 2MB CSR slice; 3MB stream + 2MB slice
//     fit one XCD's 4MB L2 -> lines fill before writeback.
// Per-edge norm computed in-place during layer 0. Each layer is ONE fused
// kernel: gather-propagate (LANES lanes/node x float4) + in-wave shuffle
// transform vs W in LDS (+bias+ReLU). Layer 4 chains x W5.
// Linearity: agg(hW * norm) == agg(h * norm) W.

namespace {

constexpr int kUsers = 100000;
constexpr int kBooks = 100000;
constexpr int kN = kUsers + kBooks;
constexpr int kE = 2000000;
constexpr int BLK = 256;

constexpr int NPART = 8;               // dest ranges == XCD count
constexpr int PART_SIZE = kN / NPART;  // 25000 nodes per range
constexpr int CAP = 262144;            // slots per bucket (mean 250k, 26 sigma)

constexpr int SCAN_T = 256;
constexpr int SCAN_PER_THREAD = 4;
constexpr int SCAN_ELEMS = SCAN_T * SCAN_PER_THREAD;             // 1024
constexpr int SCAN_BLOCKS = (kN + SCAN_ELEMS - 1) / SCAN_ELEMS;  // 196

__global__ void init_kernel(int* __restrict__ cnt, int* __restrict__ bcur) {
  int gid = blockIdx.x * blockDim.x + threadIdx.x;
  if (gid < NPART) bcur[gid] = 0;
  int stride = gridDim.x * blockDim.x;
  for (int i = gid; i < kN; i += stride) cnt[i] = 0;
}

// h16[node] = (type==0 ? user_emb[clip(nid)] : book_emb[clip(nid-U)])
__global__ void embed_kernel(const int* __restrict__ x,
                             const float* __restrict__ uemb,
                             const float* __restrict__ bemb,
                             float* __restrict__ h) {
  int gid = blockIdx.x * blockDim.x + threadIdx.x;  // exact grid kN*4
  int node = gid >> 2;
  int q = gid & 3;
  if (node >= kN) return;
  int2 xv = ((const int2*)x)[node];
  float4 v;
  if (xv.y == 0) {
    int c = min(max(xv.x, 0), kUsers - 1);
    v = ((const float4*)(uemb + (size_t)c * 16))[q];
  } else {
    int c = min(max(xv.x - kUsers, 0), kBooks - 1);
    v = ((const float4*)(bemb + (size_t)c * 16))[q];
  }
  ((float4*)h)[node * 4 + q] = v;
}

// Pass 1: partition edges into 8 dest-range buckets (SoA runs, coalesced).
__global__ void __launch_bounds__(BLK) bucketize_kernel(
    const int* __restrict__ ei, const float* __restrict__ ew,
    int* __restrict__ bcur, int* __restrict__ br, int* __restrict__ bc,
    float* __restrict__ bw) {
  __shared__ int lcnt[NPART];
  __shared__ int gbase[NPART];
  constexpr int ntiles = (kE + 1023) >> 10;
  for (int t = blockIdx.x; t < ntiles; t += gridDim.x) {
    int base = t << 10;
    if (threadIdx.x < NPART) lcnt[threadIdx.x] = 0;
    __syncthreads();
    int myoff[4], mybkt[4], myr[4], myc[4];
    float myw[4];
#pragma unroll
    for (int j = 0; j < 4; ++j) {
      int idx = base + threadIdx.x + j * BLK;
      if (idx < kE) {
        int c = ei[kE + idx];
        myr[j] = ei[idx];
        myc[j] = c;
        myw[j] = ew[idx];
        int b = c / PART_SIZE;
        mybkt[j] = b;
        myoff[j] = atomicAdd(&lcnt[b], 1);
      } else {
        mybkt[j] = -1;
      }
    }
    __syncthreads();
    if (threadIdx.x < NPART)
      gbase[threadIdx.x] = atomicAdd(&bcur[threadIdx.x], lcnt[threadIdx.x]);
    __syncthreads();
#pragma unroll
    for (int j = 0; j < 4; ++j) {
      int b = mybkt[j];
      if (b >= 0) {
        int pos = b * CAP + gbase[b] + myoff[j];
        br[pos] = myr[j];
        bc[pos] = myc[j];
        bw[pos] = myw[j];
      }
    }
    __syncthreads();  // protect lcnt before next tile
  }
}

// Pass 2: count per dest within each bucket; part = blockIdx&7 keeps the cnt
// slice and bucket stream XCD-local.
__global__ void __launch_bounds__(BLK) bcount_kernel(
    const int* __restrict__ bc, const int* __restrict__ bcur,
    int* __restrict__ cnt) {
  int part = blockIdx.x & (NPART - 1);
  int chunk = blockIdx.x >> 3;
  int nch = gridDim.x >> 3;
  int n = bcur[part];
  int per = (n + nch - 1) / nch;
  int beg = chunk * per, end = min(n, beg + per);
  const int* p = bc + part * CAP;
  for (int i = beg + threadIdx.x; i < end; i += BLK) atomicAdd(&cnt[p[i]], 1);
}

__global__ void __launch_bounds__(SCAN_T) scan_part_kernel(
    const int* __restrict__ cnt, int* __restrict__ bsum) {
  __shared__ int s[SCAN_T];
  int b = blockIdx.x;
  int t = threadIdx.x;
  int base = b * SCAN_ELEMS + t * SCAN_PER_THREAD;
  int sum = 0;
#pragma unroll
  for (int j = 0; j < SCAN_PER_THREAD; ++j) {
    int i = base + j;
    if (i < kN) sum += cnt[i];
  }
  s[t] = sum;
  __syncthreads();
  for (int off = SCAN_T / 2; off > 0; off >>= 1) {
    if (t < off) s[t] += s[t + off];
    __syncthreads();
  }
  if (t == 0) bsum[b] = s[0];
}

__global__ void __launch_bounds__(SCAN_T) scan_mid_kernel(
    const int* __restrict__ bsum, int* __restrict__ boff,
    int* __restrict__ row_ptr) {
  __shared__ int s[SCAN_T];
  int t = threadIdx.x;
  int v = (t < SCAN_BLOCKS) ? bsum[t] : 0;
  s[t] = v;
  __syncthreads();
  for (int off = 1; off < SCAN_T; off <<= 1) {
    int add = (t >= off) ? s[t - off] : 0;
    __syncthreads();
    s[t] += add;
    __syncthreads();
  }
  if (t < SCAN_BLOCKS) boff[t] = (t == 0) ? 0 : s[t - 1];
  if (t == SCAN_T - 1) row_ptr[kN] = s[SCAN_T - 1];  // == kE
}

__global__ void __launch_bounds__(SCAN_T) scan_final_kernel(
    const int* __restrict__ cnt, const int* __restrict__ boff,
    int* __restrict__ row_ptr, int* __restrict__ fill) {
  __shared__ int s[SCAN_T];
  int b = blockIdx.x;
  int t = threadIdx.x;
  int base = b * SCAN_ELEMS + t * SCAN_PER_THREAD;
  int v[SCAN_PER_THREAD];
  int sum = 0;
#pragma unroll
  for (int j = 0; j < SCAN_PER_THREAD; ++j) {
    int i = base + j;
    v[j] = (i < kN) ? cnt[i] : 0;
    sum += v[j];
  }
  s[t] = sum;
  __syncthreads();
  for (int off = 1; off < SCAN_T; off <<= 1) {
    int add = (t >= off) ? s[t - off] : 0;
    __syncthreads();
    s[t] += add;
    __syncthreads();
  }
  int run = boff[b] + ((t == 0) ? 0 : s[t - 1]);
#pragma unroll
  for (int j = 0; j < SCAN_PER_THREAD; ++j) {
    int i = base + j;
    if (i < kN) {
      row_ptr[i] = run;
      fill[i] = run;
    }
    run += v[j];
  }
}

// Pass 3: scatter bucket p into its CSR slice (2MB slice + 3MB stream fit L2).
__global__ void __launch_bounds__(BLK) bscatter_kernel(
    const int* __restrict__ br, const int* __restrict__ bc,
    const float* __restrict__ bw, const int* __restrict__ bcur,
    int* __restrict__ fill, int2* __restrict__ csr) {
  int part = blockIdx.x & (NPART - 1);
  int chunk = blockIdx.x >> 3;
  int nch = gridDim.x >> 3;
  int n = bcur[part];
  int per = (n + nch - 1) / nch;
  int beg = chunk * per, end = min(n, beg + per);
  int o = part * CAP;
  for (int i = beg + threadIdx.x; i < end; i += BLK) {
    int c = bc[o + i];
    int pos = atomicAdd(&fill[c], 1);
    csr[pos] = make_int2(br[o + i], __float_as_int(bw[o + i]));
  }
}

// deg = 1 + sum(row w); dinv = rsqrt(deg)
__global__ void deg_dinv_kernel(const int* __restrict__ row_ptr,
                                const int2* __restrict__ csr,
                                float* __restrict__ dinv) {
  int stride = gridDim.x * blockDim.x;
  for (int i = blockIdx.x * blockDim.x + threadIdx.x; i < kN; i += stride) {
    int beg = row_ptr[i];
    int end = row_ptr[i + 1];
    float s = 1.0f;  // self-loop
    for (int e = beg; e < end; ++e) s += __int_as_float(csr[e].y);
    dinv[i] = rsqrtf(fmaxf(s, 1e-12f));
  }
}

// Fused layer: propagate (gather, LANES lanes/node x float4) then in-wave
// shuffle transform z = agg @ W + b (, ReLU)(, chain x W2 32->16).
// FIRST: record.w is raw edge weight; compute norm on the fly, write back.
template <int LANES, int DOUT, bool FIRST, bool RELU, bool CHAIN16>
__global__ void __launch_bounds__(BLK) layer_kernel(
    const float* __restrict__ h, float* __restrict__ outp,
    const int* __restrict__ row_ptr, int2* csr,
    const float* __restrict__ dinv, const float* __restrict__ W,
    const float* __restrict__ bias, const float* __restrict__ W2) {
  constexpr int DIN = LANES * 4;
  constexpr int OPL = DOUT / LANES;  // outputs per lane
  __shared__ float sW[DIN * DOUT];
  __shared__ float sB[DOUT];
  __shared__ float sW2[CHAIN16 ? 32 * 16 : 1];
  for (int i = threadIdx.x; i < DIN * DOUT; i += BLK) sW[i] = W[i];
  for (int i = threadIdx.x; i < DOUT; i += BLK) sB[i] = bias[i];
  if (CHAIN16)
    for (int i = threadIdx.x; i < 32 * 16; i += BLK) sW2[i] = W2[i];
  __syncthreads();

  int gid = blockIdx.x * BLK + threadIdx.x;  // exact grid kN*LANES
  int node = gid / LANES;
  int lane = gid % LANES;
  if (node >= kN) return;
  float di = dinv[node];
  const float4* h4 = (const float4*)h;
  float4 acc = h4[node * LANES + lane];  // self loop * di^2
  float sl = di * di;
  acc.x *= sl;
  acc.y *= sl;
  acc.z *= sl;
  acc.w *= sl;
  int beg = row_ptr[node];
  int end = row_ptr[node + 1];
  for (int e = beg; e < end; ++e) {
    int2 rc = csr[e];
    float nrm;
    if (FIRST) {
      nrm = dinv[rc.x] * __int_as_float(rc.y) * di;
      if (lane == 0) ((float*)csr)[2 * e + 1] = nrm;  // finalize for later
    } else {
      nrm = __int_as_float(rc.y);
    }
    float4 hv = h4[rc.x * LANES + lane];
    acc.x = fmaf(hv.x, nrm, acc.x);
    acc.y = fmaf(hv.y, nrm, acc.y);
    acc.z = fmaf(hv.z, nrm, acc.z);
    acc.w = fmaf(hv.w, nrm, acc.w);
  }

  // transform: full DIN-vector lives across the LANES lanes of this node.
  float o[OPL];
#pragma unroll
  for (int j = 0; j < OPL; ++j) o[j] = sB[lane * OPL + j];
  float ax = acc.x, ay = acc.y, az = acc.z, aw = acc.w;
#pragma unroll
  for (int k = 0; k < DIN; ++k) {
    const int c = k & 3;
    float v = (c == 0) ? ax : (c == 1) ? ay : (c == 2) ? az : aw;
    float hk = __shfl(v, k >> 2, LANES);
    const float* wr = &sW[k * DOUT + lane * OPL];
#pragma unroll
    for (int j = 0; j < OPL; ++j) o[j] = fmaf(hk, wr[j], o[j]);
  }
  if (RELU) {
#pragma unroll
    for (int j = 0; j < OPL; ++j) o[j] = fmaxf(o[j], 0.f);
  }
  if (!CHAIN16) {
    float* op = outp + (size_t)node * DOUT + lane * OPL;
#pragma unroll
    for (int j = 0; j < OPL; j += 4)
      *(float4*)(op + j) = make_float4(o[j], o[j + 1], o[j + 2], o[j + 3]);
  } else {
    // second transform 32->16 (LANES==8, OPL==4); out dims [2*lane, 2*lane+2)
    float o2x = 0.f, o2y = 0.f;
#pragma unroll
    for (int k = 0; k < 32; ++k) {
      const int c = k & 3;
      float v = (c == 0) ? o[0] : (c == 1) ? o[1] : (c == 2) ? o[2] : o[3];
      float hk = __shfl(v, k >> 2, 8);
      o2x = fmaf(hk, sW2[k * 16 + lane * 2 + 0], o2x);
      o2y = fmaf(hk, sW2[k * 16 + lane * 2 + 1], o2y);
    }
    *(float2*)(outp + (size_t)node * 16 + lane * 2) = make_float2(o2x, o2y);
  }
}

// final: out = agg(h16) + b5 (no transform, no relu)
__global__ void __launch_bounds__(BLK) final_prop_kernel(
    const float* __restrict__ h, float* __restrict__ out,
    const int* __restrict__ row_ptr, const int2* __restrict__ csr,
    const float* __restrict__ dinv, const float* __restrict__ b5) {
  int gid = blockIdx.x * BLK + threadIdx.x;  // exact grid kN*4
  int node = gid >> 2;
  int q = gid & 3;
  if (node >= kN) return;
  float di = dinv[node];
  const float4* h4 = (const float4*)h;
  float4 acc = h4[node * 4 + q];
  float sl = di * di;
  acc.x *= sl;
  acc.y *= sl;
  acc.z *= sl;
  acc.w *= sl;
  int beg = row_ptr[node];
  int end = row_ptr[node + 1];
  for (int e = beg; e < end; ++e) {
    int2 rc = csr[e];
    float nrm = __int_as_float(rc.y);
    float4 hv = h4[rc.x * 4 + q];
    acc.x = fmaf(hv.x, nrm, acc.x);
    acc.y = fmaf(hv.y, nrm, acc.y);
    acc.z = fmaf(hv.z, nrm, acc.z);
    acc.w = fmaf(hv.w, nrm, acc.w);
  }
  float4 b = ((const float4*)b5)[q];
  acc.x += b.x;
  acc.y += b.y;
  acc.z += b.z;
  acc.w += b.w;
  ((float4*)out)[node * 4 + q] = acc;
}

inline int cdiv(long a, long b) { return (int)((a + b - 1) / b); }

}  // namespace

extern "C" void kernel_launch(void* const* d_in, const int* in_sizes, int n_in,
                              void* d_out, int out_size, void* d_ws,
                              size_t ws_size, hipStream_t stream) {
  const int* x = (const int*)d_in[0];
  const int* ei = (const int*)d_in[1];
  const float* ew = (const float*)d_in[2];
  const float* uemb = (const float*)d_in[3];
  const float* bemb = (const float*)d_in[4];
  const float* W0 = (const float*)d_in[5];
  const float* b0 = (const float*)d_in[6];
  const float* W1 = (const float*)d_in[7];
  const float* b1 = (const float*)d_in[8];
  const float* W2 = (const float*)d_in[9];
  const float* b2 = (const float*)d_in[10];
  const float* W3 = (const float*)d_in[11];
  const float* b3 = (const float*)d_in[12];
  const float* W4 = (const float*)d_in[13];
  const float* b4 = (const float*)d_in[14];
  const float* W5 = (const float*)d_in[15];
  const float* b5 = (const float*)d_in[16];
  float* out = (float*)d_out;

  char* ws = (char*)d_ws;
  size_t off = 0;
  auto walloc = [&](size_t bytes) -> void* {
    void* p = ws + off;
    off += (bytes + 255) & ~size_t(255);
    return p;
  };
  int* row_ptr = (int*)walloc((size_t)(kN + 1) * 4);
  float* dinv = (float*)walloc((size_t)kN * 4);
  int* bcur = (int*)walloc(NPART * 4);
  int2* csr = (int2*)walloc((size_t)kE * 8);
  float* hE = (float*)walloc((size_t)kN * 16 * 4);  // h16 (embed / chain out)
  float* hA = (float*)walloc((size_t)kN * 32 * 4);
  float* hB = (float*)walloc((size_t)kN * 32 * 4);
  // prep-phase scratch overlays (dead before hA/hB are first written):
  int* cnt = (int*)hA;           // kN
  int* fill = cnt + kN;          // kN
  int* bsum = fill + kN;         // SCAN_BLOCKS
  int* boff = bsum + SCAN_BLOCKS;
  int* br = (int*)hB;            // 8*CAP = 8 MB
  int* bc = br + NPART * CAP;    // 8 MB
  float* bw = (float*)(bc + NPART * CAP);  // 8 MB (24 MB total < 25.6 MB hB)
  (void)ws_size;
  (void)in_sizes;
  (void)n_in;
  (void)out_size;

  // --- graph prep ---
  init_kernel<<<cdiv(kN, BLK), BLK, 0, stream>>>(cnt, bcur);
  embed_kernel<<<kN * 4 / BLK, BLK, 0, stream>>>(x, uemb, bemb, hE);
  bucketize_kernel<<<1024, BLK, 0, stream>>>(ei, ew, bcur, br, bc, bw);
  bcount_kernel<<<256, BLK, 0, stream>>>(bc, bcur, cnt);
  scan_part_kernel<<<SCAN_BLOCKS, SCAN_T, 0, stream>>>(cnt, bsum);
  scan_mid_kernel<<<1, SCAN_T, 0, stream>>>(bsum, boff, row_ptr);
  scan_final_kernel<<<SCAN_BLOCKS, SCAN_T, 0, stream>>>(cnt, boff, row_ptr,
                                                        fill);
  bscatter_kernel<<<512, BLK, 0, stream>>>(br, bc, bw, bcur, fill, csr);
  deg_dinv_kernel<<<cdiv(kN, BLK), BLK, 0, stream>>>(row_ptr, csr, dinv);

  // --- fused layers ---
  // L0: h16 -> agg16 -> @W0+b0, relu -> hA (also finalizes csr norms)
  layer_kernel<4, 32, true, true, false><<<kN * 4 / BLK, BLK, 0, stream>>>(
      hE, hA, row_ptr, csr, dinv, W0, b0, nullptr);
  // L1..L3: 32 -> 32
  layer_kernel<8, 32, false, true, false><<<kN * 8 / BLK, BLK, 0, stream>>>(
      hA, hB, row_ptr, csr, dinv, W1, b1, nullptr);
  layer_kernel<8, 32, false, true, false><<<kN * 8 / BLK, BLK, 0, stream>>>(
      hB, hA, row_ptr, csr, dinv, W2, b2, nullptr);
  layer_kernel<8, 32, false, true, false><<<kN * 8 / BLK, BLK, 0, stream>>>(
      hA, hB, row_ptr, csr, dinv, W3, b3, nullptr);
  // L4: 32 -> 32 (relu) then chain x W5 (32->16) -> hE
  layer_kernel<8, 32, false, true, true><<<kN * 8 / BLK, BLK, 0, stream>>>(
      hB, hE, row_ptr, csr, dinv, W4, b4, W5);
  // L5: final propagate of h16 + b5 -> out
  final_prop_kernel<<<kN * 4 / BLK, BLK, 0, stream>>>(hE, out, row_ptr, csr,
                                                      dinv, b5);
}

// Round 8
// 545.425 us; speedup vs baseline: 1.3090x; 1.3090x over previous
//
#include <hip/hip_runtime.h>

// SimpleRecGNN: 6-layer GCN, N=200000 nodes, E=2000000 edges, dims 16->32(x5)->16.
// Graph build: 2-kernel radix approach.
//  1) bucketize: 8192-edge tiles -> LDS histogram over 391 sub-buckets
//     (512 dests each) -> block reserves runs -> 16B AoS records {r,c,w}.
//     Per-tile runs ~336B, active write-lines ~25KB -> L2 line-coalesced.
//  2) build: one block per sub-bucket: LDS count(512) -> LDS scan -> scatter
//     records into LDS stage -> deg/dinv -> write CSR slice + row_span
//     contiguously (zero write amplification). Replaces count/scan/scatter/deg.
// Per-edge norm computed in-place during layer 0. Each layer is ONE fused
// kernel: gather-propagate (LANES lanes/node x float4) + in-wave shuffle
// transform vs W in LDS (+bias+ReLU). Layer 4 chains x W5.
// Linearity: agg(hW * norm) == agg(h * norm) W.

namespace {

constexpr int kUsers = 100000;
constexpr int kBooks = 100000;
constexpr int kN = kUsers + kBooks;
constexpr int kE = 2000000;
constexpr int BLK = 256;

constexpr int SUBB = 512;                          // dests per sub-bucket
constexpr int NSUB = (kN + SUBB - 1) / SUBB;       // 391
constexpr int CAP2 = 5888;                         // slots/sub-bucket (mean 5120, +10.7 sigma)
constexpr int TILE = 8192;
constexpr int NTILES = (kE + TILE - 1) / TILE;     // 245

__global__ void init_kernel(int* __restrict__ bcur) {
  int gid = blockIdx.x * blockDim.x + threadIdx.x;
  if (gid < NSUB) bcur[gid] = 0;
}

// h16[node] = (type==0 ? user_emb[clip(nid)] : book_emb[clip(nid-U)])
__global__ void embed_kernel(const int* __restrict__ x,
                             const float* __restrict__ uemb,
                             const float* __restrict__ bemb,
                             float* __restrict__ h) {
  int gid = blockIdx.x * blockDim.x + threadIdx.x;  // exact grid kN*4
  int node = gid >> 2;
  int q = gid & 3;
  if (node >= kN) return;
  int2 xv = ((const int2*)x)[node];
  float4 v;
  if (xv.y == 0) {
    int c = min(max(xv.x, 0), kUsers - 1);
    v = ((const float4*)(uemb + (size_t)c * 16))[q];
  } else {
    int c = min(max(xv.x - kUsers, 0), kBooks - 1);
    v = ((const float4*)(bemb + (size_t)c * 16))[q];
  }
  ((float4*)h)[node * 4 + q] = v;
}

// Pass 1: radix-partition edges into 391 sub-bucket runs of AoS records.
__global__ void __launch_bounds__(BLK) bucketize_kernel(
    const int* __restrict__ ei, const float* __restrict__ ew,
    int* __restrict__ bcur, int4* __restrict__ recs) {
  __shared__ int hist[NSUB];
  __shared__ int gcur[NSUB];
  int base = blockIdx.x * TILE;
  int end = min(kE, base + TILE);
  for (int i = threadIdx.x; i < NSUB; i += BLK) hist[i] = 0;
  __syncthreads();
  // count (int4-vectorized; base/end multiples of 4 except final end==kE ok)
  const int4* col4 = (const int4*)(ei + kE);
  for (int i = base / 4 + threadIdx.x; i < end / 4; i += BLK) {
    int4 c = col4[i];
    atomicAdd(&hist[c.x >> 9], 1);
    atomicAdd(&hist[c.y >> 9], 1);
    atomicAdd(&hist[c.z >> 9], 1);
    atomicAdd(&hist[c.w >> 9], 1);
  }
  __syncthreads();
  for (int i = threadIdx.x; i < NSUB; i += BLK)
    gcur[i] = atomicAdd(&bcur[i], hist[i]);
  __syncthreads();
  // write records
  for (int i = base + threadIdx.x; i < end; i += BLK) {
    int r = ei[i];
    int c = ei[kE + i];
    float w = ew[i];
    int b = c >> 9;
    int pos = atomicAdd(&gcur[b], 1);  // global slot within bucket b
    pos = min(pos, CAP2 - 1);          // statistically unreachable guard
    recs[(size_t)b * CAP2 + pos] = make_int4(r, c, __float_as_int(w), 0);
  }
}

// Pass 2: one block per sub-bucket: build its CSR span entirely in LDS,
// emit contiguous CSR records {src, raw_w}, row_span {beg,end}, dinv.
__global__ void __launch_bounds__(BLK) build_kernel(
    const int4* __restrict__ recs, const int* __restrict__ bcur,
    int2* __restrict__ csr, int2* __restrict__ row_span,
    float* __restrict__ dinv) {
  __shared__ int cnt[SUBB];
  __shared__ int off[SUBB];
  __shared__ int cur[SUBB];
  __shared__ int tsum[BLK];
  __shared__ int2 stage[CAP2];  // 47 KB
  int b = blockIdx.x;
  int lo = b * SUBB;
  int nloc = min(SUBB, kN - lo);
  int n = min(bcur[b], CAP2);
  const int4* rp = recs + (size_t)b * CAP2;
  int t = threadIdx.x;
  for (int i = t; i < SUBB; i += BLK) cnt[i] = 0;
  __syncthreads();
  for (int i = t; i < n; i += BLK) atomicAdd(&cnt[rp[i].y - lo], 1);
  __syncthreads();
  // exclusive scan of 512 counters with 256 threads
  int a0 = cnt[2 * t], a1 = cnt[2 * t + 1];
  tsum[t] = a0 + a1;
  __syncthreads();
  for (int o = 1; o < BLK; o <<= 1) {
    int v = (t >= o) ? tsum[t - o] : 0;
    __syncthreads();
    tsum[t] += v;
    __syncthreads();
  }
  int tb = (t == 0) ? 0 : tsum[t - 1];
  off[2 * t] = tb;
  off[2 * t + 1] = tb + a0;
  cur[2 * t] = tb;
  cur[2 * t + 1] = tb + a0;
  __syncthreads();
  int padbase = b * CAP2;
  for (int i = t; i < nloc; i += BLK)
    row_span[lo + i] =
        make_int2(padbase + off[i], padbase + off[i] + cnt[i]);
  // scatter into LDS stage
  for (int i = t; i < n; i += BLK) {
    int4 rec = rp[i];
    int p = atomicAdd(&cur[rec.y - lo], 1);
    stage[p] = make_int2(rec.x, rec.z);
  }
  __syncthreads();
  // deg/dinv per node
  for (int i = t; i < nloc; i += BLK) {
    float s = 1.0f;  // self-loop
    int e1 = off[i] + cnt[i];
    for (int e = off[i]; e < e1; ++e) s += __int_as_float(stage[e].y);
    dinv[lo + i] = rsqrtf(fmaxf(s, 1e-12f));
  }
  // contiguous CSR write
  for (int i = t; i < n; i += BLK) csr[padbase + i] = stage[i];
}

// Fused layer: propagate (gather, LANES lanes/node x float4) then in-wave
// shuffle transform z = agg @ W + b (, ReLU)(, chain x W2 32->16).
// FIRST: record.w is raw edge weight; compute norm on the fly, write back.
template <int LANES, int DOUT, bool FIRST, bool RELU, bool CHAIN16>
__global__ void __launch_bounds__(BLK) layer_kernel(
    const float* __restrict__ h, float* __restrict__ outp,
    const int2* __restrict__ row_span, int2* csr,
    const float* __restrict__ dinv, const float* __restrict__ W,
    const float* __restrict__ bias, const float* __restrict__ W2) {
  constexpr int DIN = LANES * 4;
  constexpr int OPL = DOUT / LANES;  // outputs per lane
  __shared__ float sW[DIN * DOUT];
  __shared__ float sB[DOUT];
  __shared__ float sW2[CHAIN16 ? 32 * 16 : 1];
  for (int i = threadIdx.x; i < DIN * DOUT; i += BLK) sW[i] = W[i];
  for (int i = threadIdx.x; i < DOUT; i += BLK) sB[i] = bias[i];
  if (CHAIN16)
    for (int i = threadIdx.x; i < 32 * 16; i += BLK) sW2[i] = W2[i];
  __syncthreads();

  int gid = blockIdx.x * BLK + threadIdx.x;  // exact grid kN*LANES
  int node = gid / LANES;
  int lane = gid % LANES;
  if (node >= kN) return;
  float di = dinv[node];
  const float4* h4 = (const float4*)h;
  float4 acc = h4[node * LANES + lane];  // self loop * di^2
  float sl = di * di;
  acc.x *= sl;
  acc.y *= sl;
  acc.z *= sl;
  acc.w *= sl;
  int2 span = row_span[node];
  for (int e = span.x; e < span.y; ++e) {
    int2 rc = csr[e];
    float nrm;
    if (FIRST) {
      nrm = dinv[rc.x] * __int_as_float(rc.y) * di;
      if (lane == 0) ((float*)csr)[2 * e + 1] = nrm;  // finalize for later
    } else {
      nrm = __int_as_float(rc.y);
    }
    float4 hv = h4[rc.x * LANES + lane];
    acc.x = fmaf(hv.x, nrm, acc.x);
    acc.y = fmaf(hv.y, nrm, acc.y);
    acc.z = fmaf(hv.z, nrm, acc.z);
    acc.w = fmaf(hv.w, nrm, acc.w);
  }

  // transform: full DIN-vector lives across the LANES lanes of this node.
  float o[OPL];
#pragma unroll
  for (int j = 0; j < OPL; ++j) o[j] = sB[lane * OPL + j];
  float ax = acc.x, ay = acc.y, az = acc.z, aw = acc.w;
#pragma unroll
  for (int k = 0; k < DIN; ++k) {
    const int c = k & 3;
    float v = (c == 0) ? ax : (c == 1) ? ay : (c == 2) ? az : aw;
    float hk = __shfl(v, k >> 2, LANES);
    const float* wr = &sW[k * DOUT + lane * OPL];
#pragma unroll
    for (int j = 0; j < OPL; ++j) o[j] = fmaf(hk, wr[j], o[j]);
  }
  if (RELU) {
#pragma unroll
    for (int j = 0; j < OPL; ++j) o[j] = fmaxf(o[j], 0.f);
  }
  if (!CHAIN16) {
    float* op = outp + (size_t)node * DOUT + lane * OPL;
#pragma unroll
    for (int j = 0; j < OPL; j += 4)
      *(float4*)(op + j) = make_float4(o[j], o[j + 1], o[j + 2], o[j + 3]);
  } else {
    // second transform 32->16 (LANES==8, OPL==4); out dims [2*lane, 2*lane+2)
    float o2x = 0.f, o2y = 0.f;
#pragma unroll
    for (int k = 0; k < 32; ++k) {
      const int c = k & 3;
      float v = (c == 0) ? o[0] : (c == 1) ? o[1] : (c == 2) ? o[2] : o[3];
      float hk = __shfl(v, k >> 2, 8);
      o2x = fmaf(hk, sW2[k * 16 + lane * 2 + 0], o2x);
      o2y = fmaf(hk, sW2[k * 16 + lane * 2 + 1], o2y);
    }
    *(float2*)(outp + (size_t)node * 16 + lane * 2) = make_float2(o2x, o2y);
  }
}

// final: out = agg(h16) + b5 (no transform, no relu)
__global__ void __launch_bounds__(BLK) final_prop_kernel(
    const float* __restrict__ h, float* __restrict__ out,
    const int2* __restrict__ row_span, const int2* __restrict__ csr,
    const float* __restrict__ dinv, const float* __restrict__ b5) {
  int gid = blockIdx.x * BLK + threadIdx.x;  // exact grid kN*4
  int node = gid >> 2;
  int q = gid & 3;
  if (node >= kN) return;
  float di = dinv[node];
  const float4* h4 = (const float4*)h;
  float4 acc = h4[node * 4 + q];
  float sl = di * di;
  acc.x *= sl;
  acc.y *= sl;
  acc.z *= sl;
  acc.w *= sl;
  int2 span = row_span[node];
  for (int e = span.x; e < span.y; ++e) {
    int2 rc = csr[e];
    float nrm = __int_as_float(rc.y);
    float4 hv = h4[rc.x * 4 + q];
    acc.x = fmaf(hv.x, nrm, acc.x);
    acc.y = fmaf(hv.y, nrm, acc.y);
    acc.z = fmaf(hv.z, nrm, acc.z);
    acc.w = fmaf(hv.w, nrm, acc.w);
  }
  float4 b = ((const float4*)b5)[q];
  acc.x += b.x;
  acc.y += b.y;
  acc.z += b.z;
  acc.w += b.w;
  ((float4*)out)[node * 4 + q] = acc;
}

inline int cdiv(long a, long b) { return (int)((a + b - 1) / b); }

}  // namespace

extern "C" void kernel_launch(void* const* d_in, const int* in_sizes, int n_in,
                              void* d_out, int out_size, void* d_ws,
                              size_t ws_size, hipStream_t stream) {
  const int* x = (const int*)d_in[0];
  const int* ei = (const int*)d_in[1];
  const float* ew = (const float*)d_in[2];
  const float* uemb = (const float*)d_in[3];
  const float* bemb = (const float*)d_in[4];
  const float* W0 = (const float*)d_in[5];
  const float* b0 = (const float*)d_in[6];
  const float* W1 = (const float*)d_in[7];
  const float* b1 = (const float*)d_in[8];
  const float* W2 = (const float*)d_in[9];
  const float* b2 = (const float*)d_in[10];
  const float* W3 = (const float*)d_in[11];
  const float* b3 = (const float*)d_in[12];
  const float* W4 = (const float*)d_in[13];
  const float* b4 = (const float*)d_in[14];
  const float* W5 = (const float*)d_in[15];
  const float* b5 = (const float*)d_in[16];
  float* out = (float*)d_out;

  char* ws = (char*)d_ws;
  size_t off = 0;
  auto walloc = [&](size_t bytes) -> void* {
    void* p = ws + off;
    off += (bytes + 255) & ~size_t(255);
    return p;
  };
  int2* row_span = (int2*)walloc((size_t)kN * 8);
  float* dinv = (float*)walloc((size_t)kN * 4);
  int* bcur = (int*)walloc((size_t)NSUB * 4);
  int2* csr = (int2*)walloc((size_t)NSUB * CAP2 * 8);  // padded CSR, 18.4 MB
  float* hA = (float*)walloc((size_t)kN * 32 * 4);     // 25.6 MB
  float* hB = (float*)walloc((size_t)kN * 32 * 4);     // 25.6 MB
  // records overlay hA+hB (36.8 MB <= 51.2 MB); dead after build_kernel.
  int4* recs = (int4*)hA;
  // embed h16 lives in hA (dead after L0 reads it; L1 overwrites hA later).
  float* hE = hA;
  // L4 16-dim output lives in hB (hB dead after L3 reads it).
  float* hE2 = hB;
  (void)ws_size;
  (void)in_sizes;
  (void)n_in;
  (void)out_size;

  // --- graph prep ---
  init_kernel<<<cdiv(NSUB, BLK), BLK, 0, stream>>>(bcur);
  bucketize_kernel<<<NTILES, BLK, 0, stream>>>(ei, ew, bcur, recs);
  build_kernel<<<NSUB, BLK, 0, stream>>>(recs, bcur, csr, row_span, dinv);
  embed_kernel<<<kN * 4 / BLK, BLK, 0, stream>>>(x, uemb, bemb, hE);

  // --- fused layers (ping-pong: L0 hE->hB, L1 hB->hA, L2 hA->hB, L3 hB->hA,
  //     L4 hA->hE2(16, in hB), final hE2->out) ---
  layer_kernel<4, 32, true, true, false><<<kN * 4 / BLK, BLK, 0, stream>>>(
      hE, hB, row_span, csr, dinv, W0, b0, nullptr);
  layer_kernel<8, 32, false, true, false><<<kN * 8 / BLK, BLK, 0, stream>>>(
      hB, hA, row_span, csr, dinv, W1, b1, nullptr);
  layer_kernel<8, 32, false, true, false><<<kN * 8 / BLK, BLK, 0, stream>>>(
      hA, hB, row_span, csr, dinv, W2, b2, nullptr);
  layer_kernel<8, 32, false, true, false><<<kN * 8 / BLK, BLK, 0, stream>>>(
      hB, hA, row_span, csr, dinv, W3, b3, nullptr);
  layer_kernel<8, 32, false, true, true><<<kN * 8 / BLK, BLK, 0, stream>>>(
      hA, hE2, row_span, csr, dinv, W4, b4, W5);
  final_prop_kernel<<<kN * 4 / BLK, BLK, 0, stream>>>(hE2, out, row_span, csr,
                                                      dinv, b5);
}

// Round 9
// 465.698 us; speedup vs baseline: 1.5331x; 1.1712x over previous
//
#include <hip/hip_runtime.h>

// SimpleRecGNN: 6-layer GCN, N=200000 nodes, E=2000000 edges, dims 16->32(x5)->16.
// Graph build: 2-kernel radix (bucketize 8192-edge tiles -> 391 sub-buckets;
// build: per-sub-bucket LDS count/scan/scatter -> contiguous CSR + row_span +
// dinv). prenorm pass stores w' = dinv[src]*w per edge (no layer csr writes).
// Layers use out = di*(sum w'*h_src + di*h_self), so each layer is ONE fused
// kernel: gather-propagate (LANES lanes/node x float4, edge loop UNROLLED x4
// with 4 independent accumulators for memory-level parallelism; layers are
// gather-LATENCY bound, not BW bound) + in-wave shuffle transform vs W in LDS
// (+bias+ReLU). Layer 4 chains x W5. Linearity: agg(hW*n) == agg(h*n) W.

namespace {

constexpr int kUsers = 100000;
constexpr int kBooks = 100000;
constexpr int kN = kUsers + kBooks;
constexpr int kE = 2000000;
constexpr int BLK = 256;

constexpr int SUBB = 512;                       // dests per sub-bucket
constexpr int NSUB = (kN + SUBB - 1) / SUBB;    // 391
constexpr int CAP2 = 5888;                      // slots/sub-bucket (+10.7 sigma)
constexpr int TILE = 8192;
constexpr int NTILES = (kE + TILE - 1) / TILE;  // 245

__global__ void init_kernel(int* __restrict__ bcur) {
  int gid = blockIdx.x * blockDim.x + threadIdx.x;
  if (gid < NSUB) bcur[gid] = 0;
}

// h16[node] = (type==0 ? user_emb[clip(nid)] : book_emb[clip(nid-U)])
__global__ void embed_kernel(const int* __restrict__ x,
                             const float* __restrict__ uemb,
                             const float* __restrict__ bemb,
                             float* __restrict__ h) {
  int gid = blockIdx.x * blockDim.x + threadIdx.x;  // exact grid kN*4
  int node = gid >> 2;
  int q = gid & 3;
  if (node >= kN) return;
  int2 xv = ((const int2*)x)[node];
  float4 v;
  if (xv.y == 0) {
    int c = min(max(xv.x, 0), kUsers - 1);
    v = ((const float4*)(uemb + (size_t)c * 16))[q];
  } else {
    int c = min(max(xv.x - kUsers, 0), kBooks - 1);
    v = ((const float4*)(bemb + (size_t)c * 16))[q];
  }
  ((float4*)h)[node * 4 + q] = v;
}

// Pass 1: radix-partition edges into 391 sub-bucket runs of AoS records.
__global__ void __launch_bounds__(BLK) bucketize_kernel(
    const int* __restrict__ ei, const float* __restrict__ ew,
    int* __restrict__ bcur, int4* __restrict__ recs) {
  __shared__ int hist[NSUB];
  __shared__ int gcur[NSUB];
  int base = blockIdx.x * TILE;
  int end = min(kE, base + TILE);
  for (int i = threadIdx.x; i < NSUB; i += BLK) hist[i] = 0;
  __syncthreads();
  const int4* col4 = (const int4*)(ei + kE);
  for (int i = base / 4 + threadIdx.x; i < end / 4; i += BLK) {
    int4 c = col4[i];
    atomicAdd(&hist[c.x >> 9], 1);
    atomicAdd(&hist[c.y >> 9], 1);
    atomicAdd(&hist[c.z >> 9], 1);
    atomicAdd(&hist[c.w >> 9], 1);
  }
  __syncthreads();
  for (int i = threadIdx.x; i < NSUB; i += BLK)
    gcur[i] = atomicAdd(&bcur[i], hist[i]);
  __syncthreads();
  for (int i = base + threadIdx.x; i < end; i += BLK) {
    int r = ei[i];
    int c = ei[kE + i];
    float w = ew[i];
    int b = c >> 9;
    int pos = atomicAdd(&gcur[b], 1);
    pos = min(pos, CAP2 - 1);  // statistically unreachable guard
    recs[(size_t)b * CAP2 + pos] = make_int4(r, c, __float_as_int(w), 0);
  }
}

// Pass 2: one block per sub-bucket: build CSR span in LDS, emit contiguous
// CSR records {src, raw_w}, row_span {beg,end}, dinv.
__global__ void __launch_bounds__(BLK) build_kernel(
    const int4* __restrict__ recs, const int* __restrict__ bcur,
    int2* __restrict__ csr, int2* __restrict__ row_span,
    float* __restrict__ dinv) {
  __shared__ int cnt[SUBB];
  __shared__ int off[SUBB];
  __shared__ int cur[SUBB];
  __shared__ int tsum[BLK];
  __shared__ int2 stage[CAP2];  // 47 KB
  int b = blockIdx.x;
  int lo = b * SUBB;
  int nloc = min(SUBB, kN - lo);
  int n = min(bcur[b], CAP2);
  const int4* rp = recs + (size_t)b * CAP2;
  int t = threadIdx.x;
  for (int i = t; i < SUBB; i += BLK) cnt[i] = 0;
  __syncthreads();
  for (int i = t; i < n; i += BLK) atomicAdd(&cnt[rp[i].y - lo], 1);
  __syncthreads();
  int a0 = cnt[2 * t], a1 = cnt[2 * t + 1];
  tsum[t] = a0 + a1;
  __syncthreads();
  for (int o = 1; o < BLK; o <<= 1) {
    int v = (t >= o) ? tsum[t - o] : 0;
    __syncthreads();
    tsum[t] += v;
    __syncthreads();
  }
  int tb = (t == 0) ? 0 : tsum[t - 1];
  off[2 * t] = tb;
  off[2 * t + 1] = tb + a0;
  cur[2 * t] = tb;
  cur[2 * t + 1] = tb + a0;
  __syncthreads();
  int padbase = b * CAP2;
  for (int i = t; i < nloc; i += BLK)
    row_span[lo + i] = make_int2(padbase + off[i], padbase + off[i] + cnt[i]);
  for (int i = t; i < n; i += BLK) {
    int4 rec = rp[i];
    int p = atomicAdd(&cur[rec.y - lo], 1);
    stage[p] = make_int2(rec.x, rec.z);
  }
  __syncthreads();
  for (int i = t; i < nloc; i += BLK) {
    float s = 1.0f;  // self-loop
    int e1 = off[i] + cnt[i];
    for (int e = off[i]; e < e1; ++e) s += __int_as_float(stage[e].y);
    dinv[lo + i] = rsqrtf(fmaxf(s, 1e-12f));
  }
  for (int i = t; i < n; i += BLK) csr[padbase + i] = stage[i];
}

// Pass 3: csr.w -> dinv[src] * w (sequential stream; dinv table L2-resident)
__global__ void __launch_bounds__(BLK) prenorm_kernel(
    int2* __restrict__ csr, const int* __restrict__ bcur,
    const float* __restrict__ dinv) {
  int b = blockIdx.x;
  int n = min(bcur[b], CAP2);
  int base = b * CAP2;
  for (int i = threadIdx.x; i < n; i += BLK) {
    int2 rec = csr[base + i];
    csr[base + i].y =
        __float_as_int(dinv[rec.x] * __int_as_float(rec.y));
  }
}

// Fused layer: propagate (gather, LANES lanes/node x float4, unroll x4) then
// in-wave shuffle transform z = agg @ W + b (, ReLU)(, chain x W2 32->16).
// agg = di*(sum_e w'_e * h[src_e] + di*h_self); w' = dinv[src]*w (prenormed).
template <int LANES, int DOUT, bool RELU, bool CHAIN16>
__global__ void __launch_bounds__(BLK) layer_kernel(
    const float* __restrict__ h, float* __restrict__ outp,
    const int2* __restrict__ row_span, const int2* __restrict__ csr,
    const float* __restrict__ dinv, const float* __restrict__ W,
    const float* __restrict__ bias, const float* __restrict__ W2) {
  constexpr int DIN = LANES * 4;
  constexpr int OPL = DOUT / LANES;  // outputs per lane
  __shared__ float sW[DIN * DOUT];
  __shared__ float sB[DOUT];
  __shared__ float sW2[CHAIN16 ? 32 * 16 : 1];
  for (int i = threadIdx.x; i < DIN * DOUT; i += BLK) sW[i] = W[i];
  for (int i = threadIdx.x; i < DOUT; i += BLK) sB[i] = bias[i];
  if (CHAIN16)
    for (int i = threadIdx.x; i < 32 * 16; i += BLK) sW2[i] = W2[i];
  __syncthreads();

  int gid = blockIdx.x * BLK + threadIdx.x;  // exact grid kN*LANES
  int node = gid / LANES;
  int lane = gid % LANES;
  if (node >= kN) return;
  float di = dinv[node];
  const float4* h4 = (const float4*)h;
  float4 hs = h4[node * LANES + lane];
  int2 span = row_span[node];
  // 4 independent accumulators -> 4 gathers in flight (latency hiding)
  float4 a0 = make_float4(0.f, 0.f, 0.f, 0.f), a1 = a0, a2 = a0, a3 = a0;
  int e = span.x;
  for (; e + 3 < span.y; e += 4) {
    int2 r0 = csr[e], r1 = csr[e + 1], r2 = csr[e + 2], r3 = csr[e + 3];
    float4 h0 = h4[r0.x * LANES + lane];
    float4 h1 = h4[r1.x * LANES + lane];
    float4 h2 = h4[r2.x * LANES + lane];
    float4 h3 = h4[r3.x * LANES + lane];
    float w0 = __int_as_float(r0.y), w1 = __int_as_float(r1.y);
    float w2 = __int_as_float(r2.y), w3 = __int_as_float(r3.y);
    a0.x = fmaf(h0.x, w0, a0.x); a0.y = fmaf(h0.y, w0, a0.y);
    a0.z = fmaf(h0.z, w0, a0.z); a0.w = fmaf(h0.w, w0, a0.w);
    a1.x = fmaf(h1.x, w1, a1.x); a1.y = fmaf(h1.y, w1, a1.y);
    a1.z = fmaf(h1.z, w1, a1.z); a1.w = fmaf(h1.w, w1, a1.w);
    a2.x = fmaf(h2.x, w2, a2.x); a2.y = fmaf(h2.y, w2, a2.y);
    a2.z = fmaf(h2.z, w2, a2.z); a2.w = fmaf(h2.w, w2, a2.w);
    a3.x = fmaf(h3.x, w3, a3.x); a3.y = fmaf(h3.y, w3, a3.y);
    a3.z = fmaf(h3.z, w3, a3.z); a3.w = fmaf(h3.w, w3, a3.w);
  }
  for (; e < span.y; ++e) {
    int2 rc = csr[e];
    float w = __int_as_float(rc.y);
    float4 hv = h4[rc.x * LANES + lane];
    a0.x = fmaf(hv.x, w, a0.x); a0.y = fmaf(hv.y, w, a0.y);
    a0.z = fmaf(hv.z, w, a0.z); a0.w = fmaf(hv.w, w, a0.w);
  }
  // agg = di*(edges + di*self)
  float ax = ((a0.x + a1.x) + (a2.x + a3.x) + hs.x * di) * di;
  float ay = ((a0.y + a1.y) + (a2.y + a3.y) + hs.y * di) * di;
  float az = ((a0.z + a1.z) + (a2.z + a3.z) + hs.z * di) * di;
  float aw = ((a0.w + a1.w) + (a2.w + a3.w) + hs.w * di) * di;

  // transform: full DIN-vector lives across the LANES lanes of this node.
  float o[OPL];
#pragma unroll
  for (int j = 0; j < OPL; ++j) o[j] = sB[lane * OPL + j];
#pragma unroll
  for (int k = 0; k < DIN; ++k) {
    const int c = k & 3;
    float v = (c == 0) ? ax : (c == 1) ? ay : (c == 2) ? az : aw;
    float hk = __shfl(v, k >> 2, LANES);
    const float* wr = &sW[k * DOUT + lane * OPL];
#pragma unroll
    for (int j = 0; j < OPL; ++j) o[j] = fmaf(hk, wr[j], o[j]);
  }
  if (RELU) {
#pragma unroll
    for (int j = 0; j < OPL; ++j) o[j] = fmaxf(o[j], 0.f);
  }
  if (!CHAIN16) {
    float* op = outp + (size_t)node * DOUT + lane * OPL;
#pragma unroll
    for (int j = 0; j < OPL; j += 4)
      *(float4*)(op + j) = make_float4(o[j], o[j + 1], o[j + 2], o[j + 3]);
  } else {
    // second transform 32->16 (LANES==8, OPL==4); out dims [2*lane, 2*lane+2)
    float o2x = 0.f, o2y = 0.f;
#pragma unroll
    for (int k = 0; k < 32; ++k) {
      const int c = k & 3;
      float v = (c == 0) ? o[0] : (c == 1) ? o[1] : (c == 2) ? o[2] : o[3];
      float hk = __shfl(v, k >> 2, 8);
      o2x = fmaf(hk, sW2[k * 16 + lane * 2 + 0], o2x);
      o2y = fmaf(hk, sW2[k * 16 + lane * 2 + 1], o2y);
    }
    *(float2*)(outp + (size_t)node * 16 + lane * 2) = make_float2(o2x, o2y);
  }
}

// final: out = di*(sum w'*h + di*h_self) + b5 (no transform, no relu)
__global__ void __launch_bounds__(BLK) final_prop_kernel(
    const float* __restrict__ h, float* __restrict__ out,
    const int2* __restrict__ row_span, const int2* __restrict__ csr,
    const float* __restrict__ dinv, const float* __restrict__ b5) {
  int gid = blockIdx.x * BLK + threadIdx.x;  // exact grid kN*4
  int node = gid >> 2;
  int q = gid & 3;
  if (node >= kN) return;
  float di = dinv[node];
  const float4* h4 = (const float4*)h;
  float4 hs = h4[node * 4 + q];
  int2 span = row_span[node];
  float4 a0 = make_float4(0.f, 0.f, 0.f, 0.f), a1 = a0, a2 = a0, a3 = a0;
  int e = span.x;
  for (; e + 3 < span.y; e += 4) {
    int2 r0 = csr[e], r1 = csr[e + 1], r2 = csr[e + 2], r3 = csr[e + 3];
    float4 h0 = h4[r0.x * 4 + q];
    float4 h1 = h4[r1.x * 4 + q];
    float4 h2 = h4[r2.x * 4 + q];
    float4 h3 = h4[r3.x * 4 + q];
    float w0 = __int_as_float(r0.y), w1 = __int_as_float(r1.y);
    float w2 = __int_as_float(r2.y), w3 = __int_as_float(r3.y);
    a0.x = fmaf(h0.x, w0, a0.x); a0.y = fmaf(h0.y, w0, a0.y);
    a0.z = fmaf(h0.z, w0, a0.z); a0.w = fmaf(h0.w, w0, a0.w);
    a1.x = fmaf(h1.x, w1, a1.x); a1.y = fmaf(h1.y, w1, a1.y);
    a1.z = fmaf(h1.z, w1, a1.z); a1.w = fmaf(h1.w, w1, a1.w);
    a2.x = fmaf(h2.x, w2, a2.x); a2.y = fmaf(h2.y, w2, a2.y);
    a2.z = fmaf(h2.z, w2, a2.z); a2.w = fmaf(h2.w, w2, a2.w);
    a3.x = fmaf(h3.x, w3, a3.x); a3.y = fmaf(h3.y, w3, a3.y);
    a3.z = fmaf(h3.z, w3, a3.z); a3.w = fmaf(h3.w, w3, a3.w);
  }
  for (; e < span.y; ++e) {
    int2 rc = csr[e];
    float w = __int_as_float(rc.y);
    float4 hv = h4[rc.x * 4 + q];
    a0.x = fmaf(hv.x, w, a0.x); a0.y = fmaf(hv.y, w, a0.y);
    a0.z = fmaf(hv.z, w, a0.z); a0.w = fmaf(hv.w, w, a0.w);
  }
  float4 b = ((const float4*)b5)[q];
  float4 r;
  r.x = ((a0.x + a1.x) + (a2.x + a3.x) + hs.x * di) * di + b.x;
  r.y = ((a0.y + a1.y) + (a2.y + a3.y) + hs.y * di) * di + b.y;
  r.z = ((a0.z + a1.z) + (a2.z + a3.z) + hs.z * di) * di + b.z;
  r.w = ((a0.w + a1.w) + (a2.w + a3.w) + hs.w * di) * di + b.w;
  ((float4*)out)[node * 4 + q] = r;
}

inline int cdiv(long a, long b) { return (int)((a + b - 1) / b); }

}  // namespace

extern "C" void kernel_launch(void* const* d_in, const int* in_sizes, int n_in,
                              void* d_out, int out_size, void* d_ws,
                              size_t ws_size, hipStream_t stream) {
  const int* x = (const int*)d_in[0];
  const int* ei = (const int*)d_in[1];
  const float* ew = (const float*)d_in[2];
  const float* uemb = (const float*)d_in[3];
  const float* bemb = (const float*)d_in[4];
  const float* W0 = (const float*)d_in[5];
  const float* b0 = (const float*)d_in[6];
  const float* W1 = (const float*)d_in[7];
  const float* b1 = (const float*)d_in[8];
  const float* W2 = (const float*)d_in[9];
  const float* b2 = (const float*)d_in[10];
  const float* W3 = (const float*)d_in[11];
  const float* b3 = (const float*)d_in[12];
  const float* W4 = (const float*)d_in[13];
  const float* b4 = (const float*)d_in[14];
  const float* W5 = (const float*)d_in[15];
  const float* b5 = (const float*)d_in[16];
  float* out = (float*)d_out;

  char* ws = (char*)d_ws;
  size_t off = 0;
  auto walloc = [&](size_t bytes) -> void* {
    void* p = ws + off;
    off += (bytes + 255) & ~size_t(255);
    return p;
  };
  int2* row_span = (int2*)walloc((size_t)kN * 8);
  float* dinv = (float*)walloc((size_t)kN * 4);
  int* bcur = (int*)walloc((size_t)NSUB * 4);
  int2* csr = (int2*)walloc((size_t)NSUB * CAP2 * 8);  // padded CSR, 18.4 MB
  float* hA = (float*)walloc((size_t)kN * 32 * 4);     // 25.6 MB
  float* hB = (float*)walloc((size_t)kN * 32 * 4);     // 25.6 MB
  // records overlay hA+hB (36.8 MB <= 51.2 MB); dead after build_kernel.
  int4* recs = (int4*)hA;
  float* hE = hA;   // embed h16 (written after build)
  float* hE2 = hB;  // L4 16-dim output
  (void)ws_size;
  (void)in_sizes;
  (void)n_in;
  (void)out_size;

  // --- graph prep ---
  init_kernel<<<cdiv(NSUB, BLK), BLK, 0, stream>>>(bcur);
  bucketize_kernel<<<NTILES, BLK, 0, stream>>>(ei, ew, bcur, recs);
  build_kernel<<<NSUB, BLK, 0, stream>>>(recs, bcur, csr, row_span, dinv);
  prenorm_kernel<<<NSUB, BLK, 0, stream>>>(csr, bcur, dinv);
  embed_kernel<<<kN * 4 / BLK, BLK, 0, stream>>>(x, uemb, bemb, hE);

  // --- fused layers (L0 hE->hB, L1 hB->hA, L2 hA->hB, L3 hB->hA,
  //     L4 hA->hE2(16, in hB), final hE2->out) ---
  layer_kernel<4, 32, true, false><<<kN * 4 / BLK, BLK, 0, stream>>>(
      hE, hB, row_span, csr, dinv, W0, b0, nullptr);
  layer_kernel<8, 32, true, false><<<kN * 8 / BLK, BLK, 0, stream>>>(
      hB, hA, row_span, csr, dinv, W1, b1, nullptr);
  layer_kernel<8, 32, true, false><<<kN * 8 / BLK, BLK, 0, stream>>>(
      hA, hB, row_span, csr, dinv, W2, b2, nullptr);
  layer_kernel<8, 32, true, false><<<kN * 8 / BLK, BLK, 0, stream>>>(
      hB, hA, row_span, csr, dinv, W3, b3, nullptr);
  layer_kernel<8, 32, true, true><<<kN * 8 / BLK, BLK, 0, stream>>>(
      hA, hE2, row_span, csr, dinv, W4, b4, W5);
  final_prop_kernel<<<kN * 4 / BLK, BLK, 0, stream>>>(hE2, out, row_span, csr,
                                                      dinv, b5);
}